// Round 5
// baseline (116.323 us; speedup 1.0000x reference)
//
#include <hip/hip_runtime.h>

// NeighborPruning: LayerNorm over a size-1 axis makes every score identically
// ln_beta. All regular edges tie; stable lexsort => per-dst top-3 = the 3
// smallest original edge indices among regular (non-self-loop) edges.
// Self loops kept unconditionally.
//
// R5 (total dur is ~92-96us harness reset floor + ~16us ours; shaving ours):
//  1) np_write  — int4/float4 vectorized streaming pass (100k threads):
//     score=beta, keep=self?1:0, plus ulonglong2 slot-sentinel init.
//  2) np_insert — 64k threads, ILP-2: each iteration handles TWO 64k windows
//     concurrently (both slot reads in flight) -> half the dependent-latency
//     chain. Near-ascending arrival keeps the read filter warm (~200k CAS).
//  3) np_scatter — one thread per dst, coalesced slot read, scatter keep=1
//     to the <=3 winners.

#define SENT21 0x1FFFFFu

__device__ __forceinline__ unsigned long long pack3(unsigned a, unsigned b, unsigned c) {
    return ((unsigned long long)a << 42) | ((unsigned long long)b << 21) | (unsigned long long)c;
}

// CAS top-3 insert for one edge. cur is a pre-fetched slot value (may be stale;
// fields only decrease, so stale s2 >= current s2 and the early-out is safe).
__device__ __forceinline__ void insert_edge(unsigned long long* p,
                                            unsigned long long cur, unsigned v) {
    while (v < ((unsigned)cur & SENT21)) {          // v < s2 ?
        unsigned s0 = (unsigned)(cur >> 42) & SENT21;
        unsigned s1 = (unsigned)(cur >> 21) & SENT21;
        unsigned n0, n1, n2;
        if (v < s0)      { n0 = v;  n1 = s0; n2 = s1; }
        else if (v < s1) { n0 = s0; n1 = v;  n2 = s1; }
        else             { n0 = s0; n1 = s1; n2 = v;  }
        unsigned long long prev = atomicCAS(p, cur, pack3(n0, n1, n2));
        if (prev == cur) break;                     // installed
        cur = prev;                                 // lost race; recheck
    }
}

// Vectorized streaming pass: outputs + slot init. E is a multiple of 4 here;
// guarded tail kept for generality.
__global__ void np_write(const int4* __restrict__ src4,
                         const int4* __restrict__ dst4,
                         const float* __restrict__ ln_beta,
                         ulonglong2* __restrict__ slots2,
                         float4* __restrict__ keep4,
                         float4* __restrict__ score4, int E4, int N2) {
    int t = blockIdx.x * blockDim.x + threadIdx.x;
    if (t < N2) slots2[t] = make_ulonglong2(~0ULL, ~0ULL);  // sentinels
    if (t >= E4) return;
    const float beta = ln_beta[0];
    int4 s = src4[t];
    int4 d = dst4[t];
    float4 k;
    k.x = (s.x == d.x) ? 1.0f : 0.0f;
    k.y = (s.y == d.y) ? 1.0f : 0.0f;
    k.z = (s.z == d.z) ? 1.0f : 0.0f;
    k.w = (s.w == d.w) ? 1.0f : 0.0f;
    keep4[t]  = k;
    score4[t] = make_float4(beta, beta, beta, beta);
}

// Ordered-window CAS insert, ILP-2: two windows' edges in flight per thread.
__global__ void np_insert(const int* __restrict__ src,
                          const int* __restrict__ dst,
                          unsigned long long* __restrict__ slots, int E) {
    const int w = gridDim.x * blockDim.x;           // 64k window
    int tid = blockIdx.x * blockDim.x + threadIdx.x;
    for (int base = 0; base < E; base += 2 * w) {
        int ea = base + tid;
        int eb = ea + w;
        bool ha = (ea < E), hb = (eb < E);
        int sa = 0, da = 0, sb = 0, db = 0;
        if (ha) { sa = src[ea]; da = dst[ea]; }
        if (hb) { sb = src[eb]; db = dst[eb]; }
        bool ia = ha && (sa != da);
        bool ib = hb && (sb != db);
        unsigned long long *pa = nullptr, *pb = nullptr;
        unsigned long long ca = 0, cb = 0;
        if (ia) { pa = slots + (unsigned)da; ca = *pa; }   // both reads
        if (ib) { pb = slots + (unsigned)db; cb = *pb; }   // in flight
        if (ia) insert_edge(pa, ca, (unsigned)ea);
        if (ib) insert_edge(pb, cb, (unsigned)eb);
    }
}

// One thread per dst: coalesced slot read, scatter keep=1 to the <=3 winners.
__global__ void np_scatter(const unsigned long long* __restrict__ slots,
                           float* __restrict__ keep_out, int N) {
    int d = blockIdx.x * blockDim.x + threadIdx.x;
    if (d >= N) return;
    unsigned long long st = slots[d];
    unsigned s0 = (unsigned)(st >> 42) & SENT21;
    unsigned s1 = (unsigned)(st >> 21) & SENT21;
    unsigned s2 = (unsigned)(st      ) & SENT21;
    if (s0 != SENT21) keep_out[s0] = 1.0f;
    if (s1 != SENT21) keep_out[s1] = 1.0f;
    if (s2 != SENT21) keep_out[s2] = 1.0f;
}

extern "C" void kernel_launch(void* const* d_in, const int* in_sizes, int n_in,
                              void* d_out, int out_size, void* d_ws, size_t ws_size,
                              hipStream_t stream) {
    // inputs: 0:h [N,64] 1:q 2:edge_index [2,E] int 3:edge_batch [E]
    //         4:W1 5:b1 6:W2 7:b2 8:ln_gamma 9:ln_beta
    const int* edge_index = (const int*)d_in[2];
    const float* ln_beta  = (const float*)d_in[9];
    const int E = in_sizes[3];
    const int N = in_sizes[0] / 64;

    const int* src = edge_index;       // row 0
    const int* dst = edge_index + E;   // row 1

    float* keep_out  = (float*)d_out;       // first E floats: keep (0/1)
    float* score_out = (float*)d_out + E;   // next E floats: scores

    unsigned long long* slots = (unsigned long long*)d_ws;   // N u64 = 400 KB

    const int block = 256;
    // E=400000 (mult of 4), N=50000 (mult of 2): vector pass covers all.
    const int E4 = E / 4, N2 = N / 2;
    np_write<<<(E4 + block - 1) / block, block, 0, stream>>>(
        (const int4*)src, (const int4*)dst, ln_beta,
        (ulonglong2*)slots, (float4*)keep_out, (float4*)score_out, E4, N2);
    // 64k threads, ILP-2 over paired 64k windows.
    np_insert<<<256, block, 0, stream>>>(src, dst, slots, E);
    np_scatter<<<(N + block - 1) / block, block, 0, stream>>>(slots, keep_out, N);
}

// Round 6
// 115.590 us; speedup vs baseline: 1.0063x; 1.0063x over previous
//
#include <hip/hip_runtime.h>

// NeighborPruning: LayerNorm over a size-1 axis makes every score identically
// ln_beta. All regular edges tie; stable lexsort => per-dst top-3 = the 3
// smallest original edge indices among regular (non-self-loop) edges.
// Self loops kept unconditionally.
//
// R6 = best-of(R4,R5): R4's single-window sequential insert (ILP-2 in R5
// COOLED the ordering filter: 128k effective window -> ~+100k CAS -> +4us on
// the ~25G ops/s atomic pipe) + R5's int4-vectorized streaming write pass.
//
//  1) np_write  — int4/float4 vectorized (100k threads): score=beta,
//     keep=self?1:0, ulonglong2 slot-sentinel init (no separate memset).
//  2) np_insert — 64k threads, one 64k window per iteration, next window's
//     src/dst prefetched; ascending windows keep the CAS filter warm
//     (~150k CAS total). Stale reads direction-safe (fields only decrease).
//  3) np_scatter — one thread per dst, coalesced slot read, scatter keep=1
//     to the <=3 winners.

#define SENT21 0x1FFFFFu

__device__ __forceinline__ unsigned long long pack3(unsigned a, unsigned b, unsigned c) {
    return ((unsigned long long)a << 42) | ((unsigned long long)b << 21) | (unsigned long long)c;
}

// Vectorized streaming pass: outputs + slot init.
__global__ void np_write(const int4* __restrict__ src4,
                         const int4* __restrict__ dst4,
                         const float* __restrict__ ln_beta,
                         ulonglong2* __restrict__ slots2,
                         float4* __restrict__ keep4,
                         float4* __restrict__ score4, int E4, int N2) {
    int t = blockIdx.x * blockDim.x + threadIdx.x;
    if (t < N2) slots2[t] = make_ulonglong2(~0ULL, ~0ULL);  // sentinels
    if (t >= E4) return;
    const float beta = ln_beta[0];
    int4 s = src4[t];
    int4 d = dst4[t];
    float4 k;
    k.x = (s.x == d.x) ? 1.0f : 0.0f;
    k.y = (s.y == d.y) ? 1.0f : 0.0f;
    k.z = (s.z == d.z) ? 1.0f : 0.0f;
    k.w = (s.w == d.w) ? 1.0f : 0.0f;
    keep4[t]  = k;
    score4[t] = make_float4(beta, beta, beta, beta);
}

// Ordered-window CAS insert (R4 version). Thread count (64k) == window width:
// edges are processed in ascending 64k windows, keeping the read filter warm.
__global__ void np_insert(const int* __restrict__ src,
                          const int* __restrict__ dst,
                          unsigned long long* __restrict__ slots, int E) {
    const int stride = gridDim.x * blockDim.x;
    int e = blockIdx.x * blockDim.x + threadIdx.x;
    if (e >= E) return;
    int s = src[e];
    int d = dst[e];
    for (;;) {
        // Prefetch next window's edge while this one's slot traffic resolves.
        int e_next = e + stride;
        int s_next = 0, d_next = 0;
        bool have_next = (e_next < E);
        if (have_next) { s_next = src[e_next]; d_next = dst[e_next]; }

        if (s != d) {
            unsigned v = (unsigned)e;
            unsigned long long* p = slots + (unsigned)d;
            unsigned long long cur = *p;            // warm filter, no atomic
            while (v < ((unsigned)cur & SENT21)) {  // v < s2 ?
                unsigned s0 = (unsigned)(cur >> 42) & SENT21;
                unsigned s1 = (unsigned)(cur >> 21) & SENT21;
                unsigned n0, n1, n2;
                if (v < s0)      { n0 = v;  n1 = s0; n2 = s1; }
                else if (v < s1) { n0 = s0; n1 = v;  n2 = s1; }
                else             { n0 = s0; n1 = s1; n2 = v;  }
                unsigned long long prev = atomicCAS(p, cur, pack3(n0, n1, n2));
                if (prev == cur) break;             // installed
                cur = prev;                         // lost race; recheck
            }
        }
        if (!have_next) break;
        e = e_next; s = s_next; d = d_next;
    }
}

// One thread per dst: coalesced slot read, scatter keep=1 to the <=3 winners.
__global__ void np_scatter(const unsigned long long* __restrict__ slots,
                           float* __restrict__ keep_out, int N) {
    int d = blockIdx.x * blockDim.x + threadIdx.x;
    if (d >= N) return;
    unsigned long long st = slots[d];
    unsigned s0 = (unsigned)(st >> 42) & SENT21;
    unsigned s1 = (unsigned)(st >> 21) & SENT21;
    unsigned s2 = (unsigned)(st      ) & SENT21;
    if (s0 != SENT21) keep_out[s0] = 1.0f;
    if (s1 != SENT21) keep_out[s1] = 1.0f;
    if (s2 != SENT21) keep_out[s2] = 1.0f;
}

extern "C" void kernel_launch(void* const* d_in, const int* in_sizes, int n_in,
                              void* d_out, int out_size, void* d_ws, size_t ws_size,
                              hipStream_t stream) {
    // inputs: 0:h [N,64] 1:q 2:edge_index [2,E] int 3:edge_batch [E]
    //         4:W1 5:b1 6:W2 7:b2 8:ln_gamma 9:ln_beta
    const int* edge_index = (const int*)d_in[2];
    const float* ln_beta  = (const float*)d_in[9];
    const int E = in_sizes[3];
    const int N = in_sizes[0] / 64;

    const int* src = edge_index;       // row 0
    const int* dst = edge_index + E;   // row 1

    float* keep_out  = (float*)d_out;       // first E floats: keep (0/1)
    float* score_out = (float*)d_out + E;   // next E floats: scores

    unsigned long long* slots = (unsigned long long*)d_ws;   // N u64 = 400 KB

    const int block = 256;
    // E=400000 (mult of 4), N=50000 (mult of 2): vector pass covers all.
    const int E4 = E / 4, N2 = N / 2;
    np_write<<<(E4 + block - 1) / block, block, 0, stream>>>(
        (const int4*)src, (const int4*)dst, ln_beta,
        (ulonglong2*)slots, (float4*)keep_out, (float4*)score_out, E4, N2);
    // 64k threads, one 64k window at a time (warm filter; ~150k CAS).
    np_insert<<<256, block, 0, stream>>>(src, dst, slots, E);
    np_scatter<<<(N + block - 1) / block, block, 0, stream>>>(slots, keep_out, N);
}

// Round 7
// 112.513 us; speedup vs baseline: 1.0339x; 1.0274x over previous
//
#include <hip/hip_runtime.h>

// NeighborPruning: LayerNorm over a size-1 axis makes every score identically
// ln_beta. All regular edges tie; stable lexsort => per-dst top-3 = the 3
// smallest original edge indices among regular (non-self-loop) edges.
// Self loops kept unconditionally.
//
// R7 = exact R4 config (best measured: 111.8us). R5's ILP-2 (+4.5us: cooled
// the ordering filter -> +CAS on the ~25G ops/s atomic pipe) and R6's
// vectorized write (+3.8us vs R4, within-noise) both regressed or were noise.
//
//  1) np_write  — full grid over E: score=beta, keep=self?1:0 (coalesced
//     streaming), first N threads init slots to sentinel (no separate memset).
//  2) np_insert — 64k-thread grid-stride sweep => edges arrive in ascending
//     64k windows, keeping the plain-read CAS filter warm (~150k CAS total).
//     Next-window src/dst prefetched while current slot read/CAS resolves.
//     Stale reads are direction-safe (slot fields only decrease).
//  3) np_scatter — one thread per dst, coalesced slot read, scatter keep=1
//     to the <=3 winners.
//
// Timed-window budget (measured R3-R6): ~95-100us harness floor (256MiB ws
// re-poison at ~6.4TB/s = 42us + input restores + graph replay), ~13-15us ours.

#define SENT21 0x1FFFFFu

__device__ __forceinline__ unsigned long long pack3(unsigned a, unsigned b, unsigned c) {
    return ((unsigned long long)a << 42) | ((unsigned long long)b << 21) | (unsigned long long)c;
}

// Full-grid streaming pass: outputs + slot init.
__global__ void np_write(const int* __restrict__ src,
                         const int* __restrict__ dst,
                         const float* __restrict__ ln_beta,
                         unsigned long long* __restrict__ slots,
                         float* __restrict__ keep_out,
                         float* __restrict__ score_out, int E, int N) {
    int t = blockIdx.x * blockDim.x + threadIdx.x;
    if (t < N) slots[t] = ~0ULL;                    // sentinel (s0=s1=s2=SENT21)
    if (t >= E) return;
    score_out[t] = ln_beta[0];                      // LayerNorm(size-1) == beta
    keep_out[t] = (src[t] == dst[t]) ? 1.0f : 0.0f; // winners promoted later
}

// Ordered-window CAS insert. Thread count (64k) == window width: edges are
// globally processed in ascending 64k-index windows, keeping the read filter
// warm. Stale reads are direction-safe (fields only decrease).
__global__ void np_insert(const int* __restrict__ src,
                          const int* __restrict__ dst,
                          unsigned long long* __restrict__ slots, int E) {
    const int stride = gridDim.x * blockDim.x;
    int e = blockIdx.x * blockDim.x + threadIdx.x;
    if (e >= E) return;
    int s = src[e];
    int d = dst[e];
    for (;;) {
        // Prefetch next window's edge while this one's slot traffic resolves.
        int e_next = e + stride;
        int s_next = 0, d_next = 0;
        bool have_next = (e_next < E);
        if (have_next) { s_next = src[e_next]; d_next = dst[e_next]; }

        if (s != d) {
            unsigned v = (unsigned)e;
            unsigned long long* p = slots + (unsigned)d;
            unsigned long long cur = *p;            // warm filter, no atomic
            while (v < ((unsigned)cur & SENT21)) {  // v < s2 ?
                unsigned s0 = (unsigned)(cur >> 42) & SENT21;
                unsigned s1 = (unsigned)(cur >> 21) & SENT21;
                unsigned n0, n1, n2;
                if (v < s0)      { n0 = v;  n1 = s0; n2 = s1; }
                else if (v < s1) { n0 = s0; n1 = v;  n2 = s1; }
                else             { n0 = s0; n1 = s1; n2 = v;  }
                unsigned long long prev = atomicCAS(p, cur, pack3(n0, n1, n2));
                if (prev == cur) break;             // installed
                cur = prev;                         // lost race; recheck
            }
        }
        if (!have_next) break;
        e = e_next; s = s_next; d = d_next;
    }
}

// One thread per dst: coalesced slot read, scatter keep=1 to the <=3 winners.
__global__ void np_scatter(const unsigned long long* __restrict__ slots,
                           float* __restrict__ keep_out, int N) {
    int d = blockIdx.x * blockDim.x + threadIdx.x;
    if (d >= N) return;
    unsigned long long st = slots[d];
    unsigned s0 = (unsigned)(st >> 42) & SENT21;
    unsigned s1 = (unsigned)(st >> 21) & SENT21;
    unsigned s2 = (unsigned)(st      ) & SENT21;
    if (s0 != SENT21) keep_out[s0] = 1.0f;
    if (s1 != SENT21) keep_out[s1] = 1.0f;
    if (s2 != SENT21) keep_out[s2] = 1.0f;
}

extern "C" void kernel_launch(void* const* d_in, const int* in_sizes, int n_in,
                              void* d_out, int out_size, void* d_ws, size_t ws_size,
                              hipStream_t stream) {
    // inputs: 0:h [N,64] 1:q 2:edge_index [2,E] int 3:edge_batch [E]
    //         4:W1 5:b1 6:W2 7:b2 8:ln_gamma 9:ln_beta
    const int* edge_index = (const int*)d_in[2];
    const float* ln_beta  = (const float*)d_in[9];
    const int E = in_sizes[3];
    const int N = in_sizes[0] / 64;

    const int* src = edge_index;       // row 0
    const int* dst = edge_index + E;   // row 1

    float* keep_out  = (float*)d_out;       // first E floats: keep (0/1)
    float* score_out = (float*)d_out + E;   // next E floats: scores

    unsigned long long* slots = (unsigned long long*)d_ws;   // N u64 = 400 KB

    const int block = 256;
    np_write<<<(E + block - 1) / block, block, 0, stream>>>(
        src, dst, ln_beta, slots, keep_out, score_out, E, N);
    // 256 blocks x 256 threads = 64k window; ordering keeps CAS count ~150k.
    np_insert<<<256, block, 0, stream>>>(src, dst, slots, E);
    np_scatter<<<(N + block - 1) / block, block, 0, stream>>>(slots, keep_out, N);
}